// Round 1
// baseline (209.799 us; speedup 1.0000x reference)
//
#include <hip/hip_runtime.h>

// HierarchicalRouter: x[16384,2048] fp32, group_gate_w[8,2048], expert_gate_w[64,2048]
// out = concat(valid_mask[16384,64] as 0/1 float, normalized_weights[16384,64])
//
// R5 restructure for 2 blocks/CU (async barrier pipelines per CU):
//   * 512 blocks x 256 thr (4 waves), 32 tokens/block. Wave = (tt = w>>1 token-tile,
//     s2 = w&1 K-half); per chunk each wave does ks = s2*2+ksl, 30 MFMAs.
//   * x NEVER staged to LDS: each wave's B-fragment is 16 tokens x 128B contiguous
//     -> direct float4 global loads into regs, prefetched one chunk ahead,
//     f16 h/l split in-reg at use. (Fragment: token = lane&15, k = (lane>>4)*8+j.)
//   * LDS holds W only: compact tiles of 2048B ((g*4+ks)*2048; h at +0, l at +1024),
//     XOR-swizzle slot16 ^= (q ^ (ks<<1)) keeps staging writes AND fragment reads
//     conflict-free (<=2-way). 2 x 40960B buffers = 81920B = exactly 1/2 of 160KiB.
//   * Same exact-split math as R4: v = h + l/2048, logit = acc_hh + acc_cross/2048
//     (3 MFMA passes, error ~2^-24). Epilogue = proven R3 fp32 softmax/mask code,
//     now spread 8 tokens/wave (lane<8) instead of one serial wave.

#define NT 16384
#define NE 2048
#define NCHUNK 16
#define TOK 32
#define NTH 256
#define TILE 2048
#define BUFSZ 40960
#define LDS_BYTES 81920

typedef _Float16 v8h __attribute__((ext_vector_type(8)));
typedef float    v4f __attribute__((ext_vector_type(4)));

__global__ __launch_bounds__(NTH, 2)
void router(const float* __restrict__ x, const float* __restrict__ gw,
            const float* __restrict__ ew, float* __restrict__ out)
{
    __shared__ __align__(16) char sm[LDS_BYTES];
    const int tid  = threadIdx.x;
    const int lane = tid & 63;
    const int w    = tid >> 6;
    const int t0   = blockIdx.x * TOK;

    // ---- W staging descriptors: 1280 (gate,kslot) groups/chunk, 5 per thread ----
    const float* wsrc[5]; int who[5]; int wz[5];
    #pragma unroll
    for (int i = 0; i < 5; ++i) {
        int s = tid + i * NTH;              // 0..1279
        int gate = s >> 4, kslot = s & 15;  // gate 0..79, kslot = 8-float k-group
        int ks = kslot >> 2, q = kslot & 3;
        int m = gate & 15, g = gate >> 4;
        int swz = (q ^ (ks << 1)) & 7;      // spreads (ks,q) across 16B slots
        who[i] = (g * 4 + ks) * TILE + (((q * 16 + m) ^ swz) << 4);
        if (gate < 64)      { wz[i] = 0; wsrc[i] = ew + (size_t)gate * NE + kslot * 8; }
        else if (gate < 72) { wz[i] = 0; wsrc[i] = gw + (size_t)(gate - 64) * NE + kslot * 8; }
        else                { wz[i] = 1; wsrc[i] = ew; }   // zero-pad gates 72..79
    }

    const int tt = w >> 1, s2 = w & 1;
    // x fragment base: token = lane&15 within tile, k-quarter = lane>>4
    const float* xp = x + (size_t)(t0 + tt * 16 + (lane & 15)) * NE + (lane >> 4) * 8;

    // per-ksl LDS read offset (matches who[] swizzle; lane = q*16+m)
    int rdk[2];
    #pragma unroll
    for (int ksl = 0; ksl < 2; ++ksl) {
        int ks = s2 * 2 + ksl;
        int swz = ((lane >> 4) ^ (ks << 1)) & 7;
        rdk[ksl] = ks * TILE + ((lane ^ swz) << 4);
    }

    float4 wr[5][2], xr[2][2];

    auto wload = [&](int c) {
        const int kc = c * 128;
        #pragma unroll
        for (int i = 0; i < 5; ++i) {
            if (!wz[i]) {
                wr[i][0] = *(const float4*)(wsrc[i] + kc);
                wr[i][1] = *(const float4*)(wsrc[i] + kc + 4);
            } else {
                wr[i][0] = make_float4(0.f, 0.f, 0.f, 0.f);
                wr[i][1] = make_float4(0.f, 0.f, 0.f, 0.f);
            }
        }
    };
    auto xload = [&](int c) {
        #pragma unroll
        for (int ksl = 0; ksl < 2; ++ksl) {
            const float* p = xp + c * 128 + (s2 * 2 + ksl) * 32;
            xr[ksl][0] = *(const float4*)(p);
            xr[ksl][1] = *(const float4*)(p + 4);
        }
    };
    auto split8 = [](const float4& a, const float4& b, v8h& h, v8h& l) {
        float v[8] = {a.x, a.y, a.z, a.w, b.x, b.y, b.z, b.w};
        #pragma unroll
        for (int j = 0; j < 8; ++j) {
            _Float16 hh = (_Float16)v[j];
            h[j] = hh;
            l[j] = (_Float16)((v[j] - (float)hh) * 2048.0f);
        }
    };
    auto wcommit = [&](int buf) {
        const int bb = buf * BUFSZ;    // buf is 0/1 (double-buffer index)
        #pragma unroll
        for (int i = 0; i < 5; ++i) {
            v8h h, l;
            split8(wr[i][0], wr[i][1], h, l);
            *(v8h*)(sm + bb + who[i])        = h;
            *(v8h*)(sm + bb + who[i] + 1024) = l;
        }
    };

    v4f accHH[5], accC[5];
    #pragma unroll
    for (int g = 0; g < 5; ++g) { accHH[g] = (v4f)(0.f); accC[g] = (v4f)(0.f); }

    // ---- pipeline: one barrier/chunk; next-chunk loads (regs) fly over it ----
    wload(0); xload(0);
    wcommit(0);
    v8h Bh[2], Bl[2];
    for (int c = 0; c < NCHUNK; ++c) {
        #pragma unroll
        for (int ksl = 0; ksl < 2; ++ksl)      // split chunk c's x BEFORE xr is reloaded
            split8(xr[ksl][0], xr[ksl][1], Bh[ksl], Bl[ksl]);
        if (c + 1 < NCHUNK) { xload(c + 1); wload(c + 1); }
        __syncthreads();                       // buf[c&1] writes visible
        const int bb = (c & 1) * BUFSZ;
        #pragma unroll
        for (int ksl = 0; ksl < 2; ++ksl) {
            #pragma unroll
            for (int g = 0; g < 5; ++g) {
                const char* ab = sm + bb + g * (4 * TILE) + rdk[ksl];
                v8h Ah = *(const v8h*)(ab);
                v8h Al = *(const v8h*)(ab + 1024);
                accHH[g] = __builtin_amdgcn_mfma_f32_16x16x32_f16(Ah, Bh[ksl], accHH[g], 0, 0, 0);
                accC[g]  = __builtin_amdgcn_mfma_f32_16x16x32_f16(Ah, Bl[ksl], accC[g], 0, 0, 0);
                accC[g]  = __builtin_amdgcn_mfma_f32_16x16x32_f16(Al, Bh[ksl], accC[g], 0, 0, 0);
            }
        }
        if (c + 1 < NCHUNK) wcommit((c + 1) & 1);
    }
    __syncthreads();

    // ---- K-reduce across the two K-half waves (s2=0/1) ----
    float part[5][4];
    #pragma unroll
    for (int g = 0; g < 5; ++g)
        #pragma unroll
        for (int r = 0; r < 4; ++r)
            part[g][r] = accHH[g][r] + accC[g][r] * (1.0f / 2048.0f);

    float* red = (float*)sm;                       // 2*5*4*64 floats = 10240 B
    if (s2 == 1) {
        #pragma unroll
        for (int g = 0; g < 5; ++g)
            #pragma unroll
            for (int r = 0; r < 4; ++r)
                red[((tt * 5 + g) * 4 + r) * 64 + lane] = part[g][r];
    }
    __syncthreads();
    float* la = (float*)(sm + 10240);              // [32 tokens][84] (84: bank-spread)
    if (s2 == 0) {
        #pragma unroll
        for (int g = 0; g < 5; ++g)
            #pragma unroll
            for (int r = 0; r < 4; ++r) {
                float v = part[g][r] + red[((tt * 5 + g) * 4 + r) * 64 + lane];
                int gate  = g * 16 + (lane >> 4) * 4 + r;   // D row = gate
                int token = tt * 16 + (lane & 15);          // D col = token
                la[token * 84 + gate] = v;
            }
    }
    __syncthreads();

    // ---- per-token dual softmax + hierarchical mask (proven fp32 code), 8 tok/wave ----
    if (lane < 8) {
        const int token = w * 8 + lane;
        const float* lg = la + token * 84;         // [0..63]=experts, [64..71]=groups
        float* M  = (float*)(sm + 20992) + token * 64;
        float* Wn = (float*)(sm + 29184) + token * 64;

        float gpb[8];
        float gmax = lg[64];
        #pragma unroll
        for (int g = 1; g < 8; ++g) gmax = fmaxf(gmax, lg[64 + g]);
        float gsum = 0.f;
        #pragma unroll
        for (int g = 0; g < 8; ++g) { gpb[g] = __expf(lg[64 + g] - gmax); gsum += gpb[g]; }
        const float ginv = 1.f / gsum;

        float sel[64];
        float wsum = 0.f;
        #pragma unroll
        for (int g = 0; g < 8; ++g) {
            const float gp_ = gpb[g] * ginv;
            float emax = lg[g * 8];
            #pragma unroll
            for (int j = 1; j < 8; ++j) emax = fmaxf(emax, lg[g * 8 + j]);
            float ep[8]; float esum = 0.f;
            #pragma unroll
            for (int j = 0; j < 8; ++j) { ep[j] = __expf(lg[g * 8 + j] - emax); esum += ep[j]; }
            const float einv = 1.f / esum;
            const bool gm = gp_ >= 0.125f;
            #pragma unroll
            for (int j = 0; j < 8; ++j) {
                const float pe = ep[j] * einv;
                const bool v = gm && (pe >= 0.125f);
                const float ww = v ? gp_ * pe : 0.f;
                M[g * 8 + j] = v ? 1.f : 0.f;
                sel[g * 8 + j] = ww;
                wsum += ww;
            }
        }
        const float inv = 1.f / fmaxf(wsum, 1e-9f);
        #pragma unroll
        for (int e = 0; e < 64; ++e) Wn[e] = sel[e] * inv;
    }
    __syncthreads();

    // ---- coalesced stores: 32 tokens x 64 = 512 float4 per tensor ----
    const float4* M4 = (const float4*)(sm + 20992);
    const float4* W4 = (const float4*)(sm + 29184);
    float4* o0 = (float4*)(out + (size_t)t0 * 64);
    float4* o1 = (float4*)(out + (size_t)NT * 64 + (size_t)t0 * 64);
    o0[tid]       = M4[tid];
    o0[tid + 256] = M4[tid + 256];
    o1[tid]       = W4[tid];
    o1[tid + 256] = W4[tid + 256];
}

extern "C" void kernel_launch(void* const* d_in, const int* in_sizes, int n_in,
                              void* d_out, int out_size, void* d_ws, size_t ws_size,
                              hipStream_t stream) {
    const float* x  = (const float*)d_in[0];
    const float* gw = (const float*)d_in[1];
    const float* ew = (const float*)d_in[2];
    float* out = (float*)d_out;
    (void)d_ws; (void)ws_size;

    router<<<dim3(NT / TOK), dim3(NTH), 0, stream>>>(x, gw, ew, out);
}